// Round 2
// baseline (529.957 us; speedup 1.0000x reference)
//
#include <hip/hip_runtime.h>
#include <hip/hip_bf16.h>

#define M_TOK 2048
#define K_DIM 1024
#define E_NUM 8
#define DFF   2816
#define TOPK  2
#define NROWS (M_TOK*TOPK)   // 4096 routed rows

typedef __bf16 bf16;
typedef __bf16 bf16x8 __attribute__((ext_vector_type(8)));
typedef float  f32x4  __attribute__((ext_vector_type(4)));

// ---------------------------------------------------------------------------
// Routing: build per-expert compacted token lists, deterministically.
// 8 waves, wave e handles expert e. Pass 1 counts, pass 2 ballot-rank scatter.
// NOTE: topk_ids arrives as int32 (harness converts all ints to int32).
// ---------------------------------------------------------------------------
__global__ __launch_bounds__(512)
void route_kernel(const int* __restrict__ ids,
                  const float* __restrict__ tw,
                  int* __restrict__ counts, int* __restrict__ offs,
                  int* __restrict__ row_token, float* __restrict__ row_wgt)
{
    const int e    = threadIdx.x >> 6;
    const int lane = threadIdx.x & 63;
    __shared__ int scnt[E_NUM];

    int cnt = 0;
    for (int i0 = 0; i0 < NROWS; i0 += 64) {
        int id = ids[i0 + lane];
        cnt += __popcll(__ballot(id == e));
    }
    if (lane == 0) scnt[e] = cnt;
    __syncthreads();
    int base = 0;
    for (int j = 0; j < e; ++j) base += scnt[j];
    if (lane == 0) { counts[e] = cnt; offs[e] = base; }

    const unsigned long long ltmask = (1ull << lane) - 1ull;
    int pos = base;
    for (int i0 = 0; i0 < NROWS; i0 += 64) {
        int i = i0 + lane;
        int id = ids[i];
        unsigned long long m = __ballot(id == e);
        if (id == e) {
            int rank = __popcll(m & ltmask);
            row_token[pos + rank] = i >> 1;      // TOPK==2
            row_wgt[pos + rank]   = tw[i];
        }
        pos += __popcll(m);
    }
}

// ---------------------------------------------------------------------------
// GEMM1 + silu_and_mul.  Tile: 128 rows x 64 act-cols (gate 64 + up 64 B-rows
// stacked in Bs[0:64]/Bs[64:128]).  K-loop over K_DIM, BK=64, reg-prefetch.
// LDS rows are 128B -> XOR-swizzle 16B chunk index with (row&7)  [G4/T2].
// ---------------------------------------------------------------------------
__global__ __launch_bounds__(256, 2)
void gemm1_kernel(const float* __restrict__ X, const float* __restrict__ w1,
                  const int* __restrict__ counts, const int* __restrict__ offs,
                  const int* __restrict__ row_token, bf16* __restrict__ act)
{
    const int e  = blockIdx.z;
    const int rt = blockIdx.y;
    const int ct = blockIdx.x;              // 0..43 : 64 act cols each
    const int n  = counts[e];
    const int r0 = rt * 128;
    if (r0 >= n) return;
    const int base = offs[e];

    __shared__ __align__(16) bf16 As[128*64];
    __shared__ __align__(16) bf16 Bs[128*64];
    bf16x8* Asv = (bf16x8*)As;
    bf16x8* Bsv = (bf16x8*)Bs;

    const int t    = threadIdx.x;
    const int trow = t >> 1;                // 0..127
    const int tch  = (t & 1) * 4;           // base 16B-chunk within row

    int arl = r0 + trow; if (arl > n - 1) arl = n - 1;   // clamp (guarded on write)
    const int atok = row_token[base + arl];
    const float* aptr = X + (size_t)atok * K_DIM + (t & 1) * 32;

    const int w1row = (trow < 64) ? (ct*64 + trow) : (DFF + ct*64 + trow - 64);
    const float* bptr = w1 + ((size_t)e * (2*DFF) + w1row) * K_DIM + (t & 1) * 32;

    const int lane = t & 63, wv = t >> 6;
    const int wr = wv >> 1, wc = wv & 1;
    const int l15 = lane & 15, lq = lane >> 4;

    f32x4 accG[4][2], accU[4][2];
    #pragma unroll
    for (int m = 0; m < 4; ++m)
        #pragma unroll
        for (int nn = 0; nn < 2; ++nn) {
            accG[m][nn] = (f32x4){0.f,0.f,0.f,0.f};
            accU[m][nn] = (f32x4){0.f,0.f,0.f,0.f};
        }

    f32x4 ra[8], rb[8];
    #pragma unroll
    for (int q = 0; q < 8; ++q) {
        ra[q] = ((const f32x4*)aptr)[q];
        rb[q] = ((const f32x4*)bptr)[q];
    }

    const int KT = K_DIM / 64;   // 16
    for (int kt = 0; kt < KT; ++kt) {
        __syncthreads();
        #pragma unroll
        for (int c = 0; c < 4; ++c) {
            f32x4 lo = ra[2*c], hi = ra[2*c+1];
            bf16x8 v;
            #pragma unroll
            for (int j = 0; j < 4; ++j) { v[j] = (bf16)lo[j]; v[j+4] = (bf16)hi[j]; }
            Asv[trow*8 + ((tch + c) ^ (trow & 7))] = v;
            f32x4 lo2 = rb[2*c], hi2 = rb[2*c+1];
            bf16x8 v2;
            #pragma unroll
            for (int j = 0; j < 4; ++j) { v2[j] = (bf16)lo2[j]; v2[j+4] = (bf16)hi2[j]; }
            Bsv[trow*8 + ((tch + c) ^ (trow & 7))] = v2;
        }
        __syncthreads();
        if (kt + 1 < KT) {                   // issue next-tile loads early (T14-lite)
            const float* ap = aptr + (kt+1)*64;
            const float* bp = bptr + (kt+1)*64;
            #pragma unroll
            for (int q = 0; q < 8; ++q) {
                ra[q] = ((const f32x4*)ap)[q];
                rb[q] = ((const f32x4*)bp)[q];
            }
        }
        #pragma unroll
        for (int ks = 0; ks < 2; ++ks) {
            bf16x8 af[4], bg[2], bu[2];
            #pragma unroll
            for (int m = 0; m < 4; ++m) {
                int fr = wr*64 + m*16 + l15;
                af[m] = Asv[fr*8 + ((ks*4 + lq) ^ (fr & 7))];
            }
            #pragma unroll
            for (int nn = 0; nn < 2; ++nn) {
                int frg = wc*32 + nn*16 + l15;
                bg[nn] = Bsv[frg*8 + ((ks*4 + lq) ^ (frg & 7))];
                int fru = 64 + wc*32 + nn*16 + l15;
                bu[nn] = Bsv[fru*8 + ((ks*4 + lq) ^ (fru & 7))];
            }
            #pragma unroll
            for (int m = 0; m < 4; ++m)
                #pragma unroll
                for (int nn = 0; nn < 2; ++nn) {
                    accG[m][nn] = __builtin_amdgcn_mfma_f32_16x16x32_bf16(af[m], bg[nn], accG[m][nn], 0, 0, 0);
                    accU[m][nn] = __builtin_amdgcn_mfma_f32_16x16x32_bf16(af[m], bu[nn], accU[m][nn], 0, 0, 0);
                }
        }
    }

    // epilogue: act = silu(gate) * up, bf16 store (C/D: col=lane&15, row=(lane>>4)*4+r)
    #pragma unroll
    for (int m = 0; m < 4; ++m)
        #pragma unroll
        for (int nn = 0; nn < 2; ++nn)
            #pragma unroll
            for (int r = 0; r < 4; ++r) {
                int rl = wr*64 + m*16 + lq*4 + r;
                int grow = r0 + rl;
                if (grow < n) {
                    float g = accG[m][nn][r];
                    float u = accU[m][nn][r];
                    float a = (g / (1.f + __expf(-g))) * u;
                    int col = ct*64 + wc*32 + nn*16 + l15;
                    act[(size_t)(base + grow) * DFF + col] = (bf16)a;
                }
            }
}

// ---------------------------------------------------------------------------
// GEMM2: y = act @ w2[e]^T, epilogue scatter atomicAdd(out[token,k], wgt*y).
// Tile 128 rows x 128 out-cols, K-loop over DFF, BK=64.
// ---------------------------------------------------------------------------
__global__ __launch_bounds__(256, 2)
void gemm2_kernel(const bf16* __restrict__ act, const float* __restrict__ w2,
                  const int* __restrict__ counts, const int* __restrict__ offs,
                  const int* __restrict__ row_token, const float* __restrict__ row_wgt,
                  float* __restrict__ out)
{
    const int e  = blockIdx.z;
    const int rt = blockIdx.y;
    const int ct = blockIdx.x;               // 0..7 : 128 out cols each
    const int n  = counts[e];
    const int r0 = rt * 128;
    if (r0 >= n) return;
    const int base = offs[e];

    __shared__ __align__(16) bf16 As[128*64];
    __shared__ __align__(16) bf16 Bs[128*64];
    bf16x8* Asv = (bf16x8*)As;
    bf16x8* Bsv = (bf16x8*)Bs;

    const int t    = threadIdx.x;
    const int trow = t >> 1;
    const int tch  = (t & 1) * 4;

    int arl = r0 + trow; if (arl > n - 1) arl = n - 1;
    const bf16* aptr = act + (size_t)(base + arl) * DFF + (t & 1) * 32;
    const int kcol = ct*128 + trow;
    const float* bptr = w2 + ((size_t)e * K_DIM + kcol) * DFF + (t & 1) * 32;

    const int lane = t & 63, wv = t >> 6;
    const int wr = wv >> 1, wc = wv & 1;
    const int l15 = lane & 15, lq = lane >> 4;

    f32x4 acc[4][4];
    #pragma unroll
    for (int m = 0; m < 4; ++m)
        #pragma unroll
        for (int nn = 0; nn < 4; ++nn) acc[m][nn] = (f32x4){0.f,0.f,0.f,0.f};

    bf16x8 qa[4];
    f32x4  rb[8];
    #pragma unroll
    for (int q = 0; q < 4; ++q) qa[q] = ((const bf16x8*)aptr)[q];
    #pragma unroll
    for (int q = 0; q < 8; ++q) rb[q] = ((const f32x4*)bptr)[q];

    const int KT = DFF / 64;   // 44
    for (int kt = 0; kt < KT; ++kt) {
        __syncthreads();
        #pragma unroll
        for (int c = 0; c < 4; ++c) {
            Asv[trow*8 + ((tch + c) ^ (trow & 7))] = qa[c];
            f32x4 lo = rb[2*c], hi = rb[2*c+1];
            bf16x8 v;
            #pragma unroll
            for (int j = 0; j < 4; ++j) { v[j] = (bf16)lo[j]; v[j+4] = (bf16)hi[j]; }
            Bsv[trow*8 + ((tch + c) ^ (trow & 7))] = v;
        }
        __syncthreads();
        if (kt + 1 < KT) {
            const bf16*  ap = aptr + (kt+1)*64;
            const float* bp = bptr + (kt+1)*64;
            #pragma unroll
            for (int q = 0; q < 4; ++q) qa[q] = ((const bf16x8*)ap)[q];
            #pragma unroll
            for (int q = 0; q < 8; ++q) rb[q] = ((const f32x4*)bp)[q];
        }
        #pragma unroll
        for (int ks = 0; ks < 2; ++ks) {
            bf16x8 af[4], bf[4];
            #pragma unroll
            for (int m = 0; m < 4; ++m) {
                int fr = wr*64 + m*16 + l15;
                af[m] = Asv[fr*8 + ((ks*4 + lq) ^ (fr & 7))];
            }
            #pragma unroll
            for (int nn = 0; nn < 4; ++nn) {
                int fr = wc*64 + nn*16 + l15;
                bf[nn] = Bsv[fr*8 + ((ks*4 + lq) ^ (fr & 7))];
            }
            #pragma unroll
            for (int m = 0; m < 4; ++m)
                #pragma unroll
                for (int nn = 0; nn < 4; ++nn)
                    acc[m][nn] = __builtin_amdgcn_mfma_f32_16x16x32_bf16(af[m], bf[nn], acc[m][nn], 0, 0, 0);
        }
    }

    #pragma unroll
    for (int m = 0; m < 4; ++m)
        #pragma unroll
        for (int nn = 0; nn < 4; ++nn)
            #pragma unroll
            for (int r = 0; r < 4; ++r) {
                int rl = wr*64 + m*16 + lq*4 + r;
                int grow = r0 + rl;
                if (grow < n) {
                    int idx = base + grow;
                    int tok   = row_token[idx];
                    float wgt = row_wgt[idx];
                    int col = ct*128 + wc*64 + nn*16 + l15;
                    atomicAdd(out + (size_t)tok * K_DIM + col, wgt * acc[m][nn][r]);
                }
            }
}

// ---------------------------------------------------------------------------
extern "C" void kernel_launch(void* const* d_in, const int* in_sizes, int n_in,
                              void* d_out, int out_size, void* d_ws, size_t ws_size,
                              hipStream_t stream)
{
    const float* X   = (const float*)d_in[0];
    const float* w1  = (const float*)d_in[1];
    const float* w2  = (const float*)d_in[2];
    const float* tw  = (const float*)d_in[3];
    const int*   ids = (const int*)d_in[4];   // int64 in reference -> int32 from harness
    float* out = (float*)d_out;

    // ws layout: act (bf16 4096x2816) | row_token | row_wgt | counts | offs
    bf16* act      = (bf16*)d_ws;
    int*  row_token= (int*)((char*)d_ws + (size_t)NROWS * DFF * sizeof(bf16));
    float* row_wgt = (float*)(row_token + NROWS);
    int*  counts   = (int*)(row_wgt + NROWS);
    int*  offs     = counts + E_NUM;

    hipMemsetAsync(d_out, 0, (size_t)out_size * sizeof(float), stream);
    route_kernel<<<1, 512, 0, stream>>>(ids, tw, counts, offs, row_token, row_wgt);
    gemm1_kernel<<<dim3(DFF/64, NROWS/128, E_NUM), 256, 0, stream>>>(X, w1, counts, offs, row_token, act);
    gemm2_kernel<<<dim3(K_DIM/128, NROWS/128, E_NUM), 256, 0, stream>>>(act, w2, counts, offs, row_token, row_wgt, out);
}

// Round 3
// 436.172 us; speedup vs baseline: 1.2150x; 1.2150x over previous
//
#include <hip/hip_runtime.h>
#include <hip/hip_bf16.h>

#define M_TOK 2048
#define K_DIM 1024
#define E_NUM 8
#define DFF   2816
#define TOPK  2
#define NROWS (M_TOK*TOPK)   // 4096 routed rows

typedef __bf16 bf16;
typedef __bf16 bf16x8 __attribute__((ext_vector_type(8)));
typedef float  f32x4  __attribute__((ext_vector_type(4)));

// ---------------------------------------------------------------------------
// Routing (unchanged, verified): per-expert compacted token lists.
// ---------------------------------------------------------------------------
__global__ __launch_bounds__(512)
void route_kernel(const int* __restrict__ ids,
                  const float* __restrict__ tw,
                  int* __restrict__ counts, int* __restrict__ offs,
                  int* __restrict__ row_token, float* __restrict__ row_wgt)
{
    const int e    = threadIdx.x >> 6;
    const int lane = threadIdx.x & 63;
    __shared__ int scnt[E_NUM];

    int cnt = 0;
    for (int i0 = 0; i0 < NROWS; i0 += 64) {
        int id = ids[i0 + lane];
        cnt += __popcll(__ballot(id == e));
    }
    if (lane == 0) scnt[e] = cnt;
    __syncthreads();
    int base = 0;
    for (int j = 0; j < e; ++j) base += scnt[j];
    if (lane == 0) { counts[e] = cnt; offs[e] = base; }

    const unsigned long long ltmask = (1ull << lane) - 1ull;
    int pos = base;
    for (int i0 = 0; i0 < NROWS; i0 += 64) {
        int i = i0 + lane;
        int id = ids[i];
        unsigned long long m = __ballot(id == e);
        if (id == e) {
            int rank = __popcll(m & ltmask);
            row_token[pos + rank] = i >> 1;      // TOPK==2
            row_wgt[pos + rank]   = tw[i];
        }
        pos += __popcll(m);
    }
}

// ---------------------------------------------------------------------------
// GEMM1 + silu_and_mul. Tile 128 rows x 64 act-cols (B = 64 gate + 64 up rows).
// DOUBLE-BUFFERED LDS, one barrier per K-step: STORE(next) || COMPUTE(cur).
// ---------------------------------------------------------------------------
__global__ __launch_bounds__(256, 2)
void gemm1_kernel(const float* __restrict__ X, const float* __restrict__ w1,
                  const int* __restrict__ counts, const int* __restrict__ offs,
                  const int* __restrict__ row_token, bf16* __restrict__ act)
{
    const int e  = blockIdx.z;
    const int rt = blockIdx.y;
    const int ct = blockIdx.x;              // 0..43
    const int n  = counts[e];
    const int r0 = rt * 128;
    if (r0 >= n) return;
    const int base = offs[e];

    __shared__ __align__(16) bf16 As[2][128*64];
    __shared__ __align__(16) bf16 Bs[2][128*64];
    bf16x8* Asv = (bf16x8*)As;              // buffer stride 1024 (bf16x8 units)
    bf16x8* Bsv = (bf16x8*)Bs;

    const int t    = threadIdx.x;
    const int trow = t >> 1;                // 0..127
    const int tch  = (t & 1) * 4;

    int arl = r0 + trow; if (arl > n - 1) arl = n - 1;
    const int atok = row_token[base + arl];
    const float* aptr = X + (size_t)atok * K_DIM + (t & 1) * 32;

    const int w1row = (trow < 64) ? (ct*64 + trow) : (DFF + ct*64 + trow - 64);
    const float* bptr = w1 + ((size_t)e * (2*DFF) + w1row) * K_DIM + (t & 1) * 32;

    const int lane = t & 63, wv = t >> 6;
    const int wr = wv >> 1, wc = wv & 1;
    const int l15 = lane & 15, lq = lane >> 4;

    f32x4 accG[4][2], accU[4][2];
    #pragma unroll
    for (int m = 0; m < 4; ++m)
        #pragma unroll
        for (int nn = 0; nn < 2; ++nn) {
            accG[m][nn] = (f32x4){0.f,0.f,0.f,0.f};
            accU[m][nn] = (f32x4){0.f,0.f,0.f,0.f};
        }

    f32x4 ra[8], rb[8];

#define G1_LOAD(KT_) do { \
    const float* ap_ = aptr + (KT_)*64; const float* bp_ = bptr + (KT_)*64; \
    _Pragma("unroll") for (int q = 0; q < 8; ++q) { \
        ra[q] = ((const f32x4*)ap_)[q]; rb[q] = ((const f32x4*)bp_)[q]; } \
    } while (0)

#define G1_STORE(B_) do { \
    _Pragma("unroll") for (int c = 0; c < 4; ++c) { \
        f32x4 lo = ra[2*c], hi = ra[2*c+1]; bf16x8 v; \
        _Pragma("unroll") for (int j = 0; j < 4; ++j) { v[j]=(bf16)lo[j]; v[j+4]=(bf16)hi[j]; } \
        Asv[(B_)*1024 + trow*8 + ((tch + c) ^ (trow & 7))] = v; \
        f32x4 lo2 = rb[2*c], hi2 = rb[2*c+1]; bf16x8 v2; \
        _Pragma("unroll") for (int j = 0; j < 4; ++j) { v2[j]=(bf16)lo2[j]; v2[j+4]=(bf16)hi2[j]; } \
        Bsv[(B_)*1024 + trow*8 + ((tch + c) ^ (trow & 7))] = v2; \
    } } while (0)

    const int KT = K_DIM / 64;   // 16
    G1_LOAD(0);
    G1_STORE(0);
    G1_LOAD(1);
    __syncthreads();

    for (int kt = 0; kt < KT; ++kt) {
        const int cur = kt & 1;
        if (kt + 1 < KT) {
            G1_STORE(cur ^ 1);               // regs hold tile kt+1
            if (kt + 2 < KT) G1_LOAD(kt + 2);
        }
        #pragma unroll
        for (int ks = 0; ks < 2; ++ks) {
            bf16x8 af[4], bg[2], bu[2];
            #pragma unroll
            for (int m = 0; m < 4; ++m) {
                int fr = wr*64 + m*16 + l15;
                af[m] = Asv[cur*1024 + fr*8 + ((ks*4 + lq) ^ (fr & 7))];
            }
            #pragma unroll
            for (int nn = 0; nn < 2; ++nn) {
                int frg = wc*32 + nn*16 + l15;
                bg[nn] = Bsv[cur*1024 + frg*8 + ((ks*4 + lq) ^ (frg & 7))];
                int fru = 64 + wc*32 + nn*16 + l15;
                bu[nn] = Bsv[cur*1024 + fru*8 + ((ks*4 + lq) ^ (fru & 7))];
            }
            #pragma unroll
            for (int m = 0; m < 4; ++m)
                #pragma unroll
                for (int nn = 0; nn < 2; ++nn) {
                    accG[m][nn] = __builtin_amdgcn_mfma_f32_16x16x32_bf16(af[m], bg[nn], accG[m][nn], 0, 0, 0);
                    accU[m][nn] = __builtin_amdgcn_mfma_f32_16x16x32_bf16(af[m], bu[nn], accU[m][nn], 0, 0, 0);
                }
        }
        __syncthreads();
    }

    // epilogue: act = silu(gate) * up  (C/D: col=lane&15, row=(lane>>4)*4+r)
    #pragma unroll
    for (int m = 0; m < 4; ++m)
        #pragma unroll
        for (int nn = 0; nn < 2; ++nn)
            #pragma unroll
            for (int r = 0; r < 4; ++r) {
                int rl = wr*64 + m*16 + lq*4 + r;
                int grow = r0 + rl;
                if (grow < n) {
                    float g = accG[m][nn][r];
                    float u = accU[m][nn][r];
                    float a = (g / (1.f + __expf(-g))) * u;
                    int col = ct*64 + wc*32 + nn*16 + l15;
                    act[(size_t)(base + grow) * DFF + col] = (bf16)a;
                }
            }
#undef G1_LOAD
#undef G1_STORE
}

// ---------------------------------------------------------------------------
// GEMM2: y = act @ w2[e]^T, atomic scatter epilogue. Tile 128 x 128.
// Double-buffered LDS + DFF split in 2 (KSPLIT) for occupancy (512 blocks).
// ---------------------------------------------------------------------------
#define KSPLIT 2
#define KT2    (DFF / 64 / KSPLIT)   // 22

__global__ __launch_bounds__(256, 2)
void gemm2_kernel(const bf16* __restrict__ act, const float* __restrict__ w2,
                  const int* __restrict__ counts, const int* __restrict__ offs,
                  const int* __restrict__ row_token, const float* __restrict__ row_wgt,
                  float* __restrict__ out)
{
    const int e   = blockIdx.z;
    const int rt  = blockIdx.y;
    const int ct  = blockIdx.x >> 1;          // 0..7 : 128 out cols
    const int ksp = blockIdx.x & 1;           // DFF half
    const int n   = counts[e];
    const int r0  = rt * 128;
    if (r0 >= n) return;
    const int base = offs[e];

    __shared__ __align__(16) bf16 As[2][128*64];
    __shared__ __align__(16) bf16 Bs[2][128*64];
    bf16x8* Asv = (bf16x8*)As;
    bf16x8* Bsv = (bf16x8*)Bs;

    const int t    = threadIdx.x;
    const int trow = t >> 1;
    const int tch  = (t & 1) * 4;

    int arl = r0 + trow; if (arl > n - 1) arl = n - 1;
    const bf16* aptr = act + (size_t)(base + arl) * DFF + ksp*(DFF/KSPLIT) + (t & 1) * 32;
    const int kcol = ct*128 + trow;
    const float* bptr = w2 + ((size_t)e * K_DIM + kcol) * DFF + ksp*(DFF/KSPLIT) + (t & 1) * 32;

    const int lane = t & 63, wv = t >> 6;
    const int wr = wv >> 1, wc = wv & 1;
    const int l15 = lane & 15, lq = lane >> 4;

    f32x4 acc[4][4];
    #pragma unroll
    for (int m = 0; m < 4; ++m)
        #pragma unroll
        for (int nn = 0; nn < 4; ++nn) acc[m][nn] = (f32x4){0.f,0.f,0.f,0.f};

    bf16x8 qa[4];
    f32x4  rb[8];

#define G2_LOAD(KT_) do { \
    const bf16* ap_ = aptr + (KT_)*64; const float* bp_ = bptr + (KT_)*64; \
    _Pragma("unroll") for (int q = 0; q < 4; ++q) qa[q] = ((const bf16x8*)ap_)[q]; \
    _Pragma("unroll") for (int q = 0; q < 8; ++q) rb[q] = ((const f32x4*)bp_)[q]; \
    } while (0)

#define G2_STORE(B_) do { \
    _Pragma("unroll") for (int c = 0; c < 4; ++c) { \
        Asv[(B_)*1024 + trow*8 + ((tch + c) ^ (trow & 7))] = qa[c]; \
        f32x4 lo = rb[2*c], hi = rb[2*c+1]; bf16x8 v; \
        _Pragma("unroll") for (int j = 0; j < 4; ++j) { v[j]=(bf16)lo[j]; v[j+4]=(bf16)hi[j]; } \
        Bsv[(B_)*1024 + trow*8 + ((tch + c) ^ (trow & 7))] = v; \
    } } while (0)

    G2_LOAD(0);
    G2_STORE(0);
    G2_LOAD(1);
    __syncthreads();

    for (int kt = 0; kt < KT2; ++kt) {
        const int cur = kt & 1;
        if (kt + 1 < KT2) {
            G2_STORE(cur ^ 1);
            if (kt + 2 < KT2) G2_LOAD(kt + 2);
        }
        #pragma unroll
        for (int ks = 0; ks < 2; ++ks) {
            bf16x8 af[4], bf[4];
            #pragma unroll
            for (int m = 0; m < 4; ++m) {
                int fr = wr*64 + m*16 + l15;
                af[m] = Asv[cur*1024 + fr*8 + ((ks*4 + lq) ^ (fr & 7))];
            }
            #pragma unroll
            for (int nn = 0; nn < 4; ++nn) {
                int fr = wc*64 + nn*16 + l15;
                bf[nn] = Bsv[cur*1024 + fr*8 + ((ks*4 + lq) ^ (fr & 7))];
            }
            #pragma unroll
            for (int m = 0; m < 4; ++m)
                #pragma unroll
                for (int nn = 0; nn < 4; ++nn)
                    acc[m][nn] = __builtin_amdgcn_mfma_f32_16x16x32_bf16(af[m], bf[nn], acc[m][nn], 0, 0, 0);
        }
        __syncthreads();
    }

    #pragma unroll
    for (int m = 0; m < 4; ++m)
        #pragma unroll
        for (int nn = 0; nn < 4; ++nn)
            #pragma unroll
            for (int r = 0; r < 4; ++r) {
                int rl = wr*64 + m*16 + lq*4 + r;
                int grow = r0 + rl;
                if (grow < n) {
                    int idx = base + grow;
                    int tok   = row_token[idx];
                    float wgt = row_wgt[idx];
                    int col = ct*128 + wc*64 + nn*16 + l15;
                    atomicAdd(out + (size_t)tok * K_DIM + col, wgt * acc[m][nn][r]);
                }
            }
#undef G2_LOAD
#undef G2_STORE
}

// ---------------------------------------------------------------------------
extern "C" void kernel_launch(void* const* d_in, const int* in_sizes, int n_in,
                              void* d_out, int out_size, void* d_ws, size_t ws_size,
                              hipStream_t stream)
{
    const float* X   = (const float*)d_in[0];
    const float* w1  = (const float*)d_in[1];
    const float* w2  = (const float*)d_in[2];
    const float* tw  = (const float*)d_in[3];
    const int*   ids = (const int*)d_in[4];   // int64 in reference -> int32 from harness
    float* out = (float*)d_out;

    // ws layout: act (bf16 4096x2816) | row_token | row_wgt | counts | offs
    bf16* act      = (bf16*)d_ws;
    int*  row_token= (int*)((char*)d_ws + (size_t)NROWS * DFF * sizeof(bf16));
    float* row_wgt = (float*)(row_token + NROWS);
    int*  counts   = (int*)(row_wgt + NROWS);
    int*  offs     = counts + E_NUM;

    hipMemsetAsync(d_out, 0, (size_t)out_size * sizeof(float), stream);
    route_kernel<<<1, 512, 0, stream>>>(ids, tw, counts, offs, row_token, row_wgt);
    gemm1_kernel<<<dim3(DFF/64, NROWS/128, E_NUM), 256, 0, stream>>>(X, w1, counts, offs, row_token, act);
    gemm2_kernel<<<dim3((K_DIM/128)*KSPLIT, NROWS/128, E_NUM), 256, 0, stream>>>(act, w2, counts, offs, row_token, row_wgt, out);
}

// Round 4
// 275.363 us; speedup vs baseline: 1.9246x; 1.5840x over previous
//
#include <hip/hip_runtime.h>
#include <hip/hip_bf16.h>

#define M_TOK 2048
#define K_DIM 1024
#define E_NUM 8
#define DFF   2816
#define TOPK  2
#define NROWS (M_TOK*TOPK)   // 4096 routed rows

typedef __bf16 bf16;
typedef __bf16 bf16x8 __attribute__((ext_vector_type(8)));
typedef float  f32x4  __attribute__((ext_vector_type(4)));

// ---------------------------------------------------------------------------
// Routing (unchanged, verified): per-expert compacted token lists.
// ---------------------------------------------------------------------------
__global__ __launch_bounds__(512)
void route_kernel(const int* __restrict__ ids,
                  const float* __restrict__ tw,
                  int* __restrict__ counts, int* __restrict__ offs,
                  int* __restrict__ row_token, float* __restrict__ row_wgt)
{
    const int e    = threadIdx.x >> 6;
    const int lane = threadIdx.x & 63;
    __shared__ int scnt[E_NUM];

    int cnt = 0;
    for (int i0 = 0; i0 < NROWS; i0 += 64) {
        int id = ids[i0 + lane];
        cnt += __popcll(__ballot(id == e));
    }
    if (lane == 0) scnt[e] = cnt;
    __syncthreads();
    int base = 0;
    for (int j = 0; j < e; ++j) base += scnt[j];
    if (lane == 0) { counts[e] = cnt; offs[e] = base; }

    const unsigned long long ltmask = (1ull << lane) - 1ull;
    int pos = base;
    for (int i0 = 0; i0 < NROWS; i0 += 64) {
        int i = i0 + lane;
        int id = ids[i];
        unsigned long long m = __ballot(id == e);
        if (id == e) {
            int rank = __popcll(m & ltmask);
            row_token[pos + rank] = i >> 1;      // TOPK==2
            row_wgt[pos + rank]   = tw[i];
        }
        pos += __popcll(m);
    }
}

// ---------------------------------------------------------------------------
// GEMM1 + silu_and_mul. Tile 128 rows x 64 act-cols (B = 64 gate + 64 up rows).
// Double-buffered LDS. COALESCED loads: thread t -> rows q*32+(t>>3), 32B unit
// t&7; a wave covers 8 rows x 256B fully contiguous (was: 32 rows half-lines).
// ---------------------------------------------------------------------------
__global__ __launch_bounds__(256, 2)
void gemm1_kernel(const float* __restrict__ X, const float* __restrict__ w1,
                  const int* __restrict__ counts, const int* __restrict__ offs,
                  const int* __restrict__ row_token, bf16* __restrict__ act)
{
    const int e  = blockIdx.z;
    const int rt = blockIdx.y;
    const int ct = blockIdx.x;              // 0..43
    const int n  = counts[e];
    const int r0 = rt * 128;
    if (r0 >= n) return;
    const int base = offs[e];

    __shared__ __align__(16) bf16 As[2][128*64];
    __shared__ __align__(16) bf16 Bs[2][128*64];
    bf16x8* Asv = (bf16x8*)As;              // buffer stride 1024 (bf16x8 units)
    bf16x8* Bsv = (bf16x8*)Bs;

    const int t   = threadIdx.x;
    const int rq0 = t >> 3;                 // 0..31
    const int ju  = t & 7;                  // 32B unit within 256B row-slice

    const float* aRow[4];
    const float* bRow[4];
    #pragma unroll
    for (int q = 0; q < 4; ++q) {
        int rl = r0 + q*32 + rq0; if (rl > n - 1) rl = n - 1;
        aRow[q] = X + (size_t)row_token[base + rl] * K_DIM + ju*8;
        int brow = q*32 + rq0;              // 0..127
        int w1row = (brow < 64) ? (ct*64 + brow) : (DFF + ct*64 + brow - 64);
        bRow[q] = w1 + ((size_t)e * (2*DFF) + w1row) * K_DIM + ju*8;
    }

    const int lane = t & 63, wv = t >> 6;
    const int wr = wv >> 1, wc = wv & 1;
    const int l15 = lane & 15, lq = lane >> 4;

    f32x4 accG[4][2], accU[4][2];
    #pragma unroll
    for (int m = 0; m < 4; ++m)
        #pragma unroll
        for (int nn = 0; nn < 2; ++nn) {
            accG[m][nn] = (f32x4){0.f,0.f,0.f,0.f};
            accU[m][nn] = (f32x4){0.f,0.f,0.f,0.f};
        }

    f32x4 ra[8], rb[8];

#define G1_LOAD(KT_) do { \
    _Pragma("unroll") for (int q = 0; q < 4; ++q) { \
        const f32x4* ap_ = (const f32x4*)(aRow[q] + (KT_)*64); \
        ra[2*q] = ap_[0]; ra[2*q+1] = ap_[1]; \
        const f32x4* bp_ = (const f32x4*)(bRow[q] + (KT_)*64); \
        rb[2*q] = bp_[0]; rb[2*q+1] = bp_[1]; \
    } } while (0)

#define G1_STORE(B_) do { \
    _Pragma("unroll") for (int q = 0; q < 4; ++q) { \
        int rq_ = q*32 + rq0; \
        f32x4 lo = ra[2*q], hi = ra[2*q+1]; bf16x8 v; \
        _Pragma("unroll") for (int j = 0; j < 4; ++j) { v[j]=(bf16)lo[j]; v[j+4]=(bf16)hi[j]; } \
        Asv[(B_)*1024 + rq_*8 + (ju ^ (rq_ & 7))] = v; \
        f32x4 lo2 = rb[2*q], hi2 = rb[2*q+1]; bf16x8 v2; \
        _Pragma("unroll") for (int j = 0; j < 4; ++j) { v2[j]=(bf16)lo2[j]; v2[j+4]=(bf16)hi2[j]; } \
        Bsv[(B_)*1024 + rq_*8 + (ju ^ (rq_ & 7))] = v2; \
    } } while (0)

    const int KT = K_DIM / 64;   // 16
    G1_LOAD(0);
    G1_STORE(0);
    G1_LOAD(1);
    __syncthreads();

    for (int kt = 0; kt < KT; ++kt) {
        const int cur = kt & 1;
        if (kt + 1 < KT) {
            G1_STORE(cur ^ 1);               // regs hold tile kt+1
            if (kt + 2 < KT) G1_LOAD(kt + 2);
        }
        #pragma unroll
        for (int ks = 0; ks < 2; ++ks) {
            bf16x8 af[4], bg[2], bu[2];
            #pragma unroll
            for (int m = 0; m < 4; ++m) {
                int fr = wr*64 + m*16 + l15;
                af[m] = Asv[cur*1024 + fr*8 + ((ks*4 + lq) ^ (fr & 7))];
            }
            #pragma unroll
            for (int nn = 0; nn < 2; ++nn) {
                int frg = wc*32 + nn*16 + l15;
                bg[nn] = Bsv[cur*1024 + frg*8 + ((ks*4 + lq) ^ (frg & 7))];
                int fru = 64 + wc*32 + nn*16 + l15;
                bu[nn] = Bsv[cur*1024 + fru*8 + ((ks*4 + lq) ^ (fru & 7))];
            }
            #pragma unroll
            for (int m = 0; m < 4; ++m)
                #pragma unroll
                for (int nn = 0; nn < 2; ++nn) {
                    accG[m][nn] = __builtin_amdgcn_mfma_f32_16x16x32_bf16(af[m], bg[nn], accG[m][nn], 0, 0, 0);
                    accU[m][nn] = __builtin_amdgcn_mfma_f32_16x16x32_bf16(af[m], bu[nn], accU[m][nn], 0, 0, 0);
                }
        }
        __syncthreads();
    }

    // epilogue: act = silu(gate) * up  (C/D: col=lane&15, row=(lane>>4)*4+r)
    #pragma unroll
    for (int m = 0; m < 4; ++m)
        #pragma unroll
        for (int nn = 0; nn < 2; ++nn)
            #pragma unroll
            for (int r = 0; r < 4; ++r) {
                int rl = wr*64 + m*16 + lq*4 + r;
                int grow = r0 + rl;
                if (grow < n) {
                    float g = accG[m][nn][r];
                    float u = accU[m][nn][r];
                    float a = (g / (1.f + __expf(-g))) * u;
                    int col = ct*64 + wc*32 + nn*16 + l15;
                    act[(size_t)(base + grow) * DFF + col] = (bf16)a;
                }
            }
#undef G1_LOAD
#undef G1_STORE
}

// ---------------------------------------------------------------------------
// GEMM2: y = act @ w2[e]^T, atomic scatter epilogue. Tile 128 x 128.
// Double-buffered LDS + DFF KSPLIT=2. Coalesced mapping like gemm1.
// A (act, bf16): rows q*64+(t>>2), 32B unit t&3. B (w2, f32): like gemm1 B.
// ---------------------------------------------------------------------------
#define KSPLIT 2
#define KT2    (DFF / 64 / KSPLIT)   // 22

__global__ __launch_bounds__(256, 2)
void gemm2_kernel(const bf16* __restrict__ act, const float* __restrict__ w2,
                  const int* __restrict__ counts, const int* __restrict__ offs,
                  const int* __restrict__ row_token, const float* __restrict__ row_wgt,
                  float* __restrict__ out)
{
    const int e   = blockIdx.z;
    const int rt  = blockIdx.y;
    const int ct  = blockIdx.x >> 1;          // 0..7 : 128 out cols
    const int ksp = blockIdx.x & 1;           // DFF half
    const int n   = counts[e];
    const int r0  = rt * 128;
    if (r0 >= n) return;
    const int base = offs[e];

    __shared__ __align__(16) bf16 As[2][128*64];
    __shared__ __align__(16) bf16 Bs[2][128*64];
    bf16x8* Asv = (bf16x8*)As;
    bf16x8* Bsv = (bf16x8*)Bs;

    const int t = threadIdx.x;
    const int rqa = t >> 2, jua = t & 3;      // A: 4 units(32B) per 128B row
    const int rqb = t >> 3, jub = t & 7;      // B: 8 units(32B) per 256B row

    const bf16* aRow[2];
    #pragma unroll
    for (int q = 0; q < 2; ++q) {
        int rl = r0 + q*64 + rqa; if (rl > n - 1) rl = n - 1;
        aRow[q] = act + (size_t)(base + rl) * DFF + ksp*(DFF/KSPLIT) + jua*16;
    }
    const float* bRow[4];
    #pragma unroll
    for (int q = 0; q < 4; ++q) {
        int brow = ct*128 + q*32 + rqb;
        bRow[q] = w2 + ((size_t)e * K_DIM + brow) * DFF + ksp*(DFF/KSPLIT) + jub*8;
    }

    const int lane = t & 63, wv = t >> 6;
    const int wr = wv >> 1, wc = wv & 1;
    const int l15 = lane & 15, lq = lane >> 4;

    f32x4 acc[4][4];
    #pragma unroll
    for (int m = 0; m < 4; ++m)
        #pragma unroll
        for (int nn = 0; nn < 4; ++nn) acc[m][nn] = (f32x4){0.f,0.f,0.f,0.f};

    bf16x8 qa[4];
    f32x4  rb[8];

#define G2_LOAD(KT_) do { \
    _Pragma("unroll") for (int q = 0; q < 2; ++q) { \
        const bf16x8* ap_ = (const bf16x8*)(aRow[q] + (KT_)*64); \
        qa[2*q] = ap_[0]; qa[2*q+1] = ap_[1]; \
    } \
    _Pragma("unroll") for (int q = 0; q < 4; ++q) { \
        const f32x4* bp_ = (const f32x4*)(bRow[q] + (KT_)*64); \
        rb[2*q] = bp_[0]; rb[2*q+1] = bp_[1]; \
    } } while (0)

#define G2_STORE(B_) do { \
    _Pragma("unroll") for (int q = 0; q < 2; ++q) { \
        int ra_ = q*64 + rqa; \
        Asv[(B_)*1024 + ra_*8 + ((2*jua)   ^ (ra_ & 7))] = qa[2*q]; \
        Asv[(B_)*1024 + ra_*8 + ((2*jua+1) ^ (ra_ & 7))] = qa[2*q+1]; \
    } \
    _Pragma("unroll") for (int q = 0; q < 4; ++q) { \
        int rb_ = q*32 + rqb; \
        f32x4 lo = rb[2*q], hi = rb[2*q+1]; bf16x8 v; \
        _Pragma("unroll") for (int j = 0; j < 4; ++j) { v[j]=(bf16)lo[j]; v[j+4]=(bf16)hi[j]; } \
        Bsv[(B_)*1024 + rb_*8 + (jub ^ (rb_ & 7))] = v; \
    } } while (0)

    G2_LOAD(0);
    G2_STORE(0);
    G2_LOAD(1);
    __syncthreads();

    for (int kt = 0; kt < KT2; ++kt) {
        const int cur = kt & 1;
        if (kt + 1 < KT2) {
            G2_STORE(cur ^ 1);
            if (kt + 2 < KT2) G2_LOAD(kt + 2);
        }
        #pragma unroll
        for (int ks = 0; ks < 2; ++ks) {
            bf16x8 af[4], bf[4];
            #pragma unroll
            for (int m = 0; m < 4; ++m) {
                int fr = wr*64 + m*16 + l15;
                af[m] = Asv[cur*1024 + fr*8 + ((ks*4 + lq) ^ (fr & 7))];
            }
            #pragma unroll
            for (int nn = 0; nn < 4; ++nn) {
                int fr = wc*64 + nn*16 + l15;
                bf[nn] = Bsv[cur*1024 + fr*8 + ((ks*4 + lq) ^ (fr & 7))];
            }
            #pragma unroll
            for (int m = 0; m < 4; ++m)
                #pragma unroll
                for (int nn = 0; nn < 4; ++nn)
                    acc[m][nn] = __builtin_amdgcn_mfma_f32_16x16x32_bf16(af[m], bf[nn], acc[m][nn], 0, 0, 0);
        }
        __syncthreads();
    }

    #pragma unroll
    for (int m = 0; m < 4; ++m)
        #pragma unroll
        for (int nn = 0; nn < 4; ++nn)
            #pragma unroll
            for (int r = 0; r < 4; ++r) {
                int rl = wr*64 + m*16 + lq*4 + r;
                int grow = r0 + rl;
                if (grow < n) {
                    int idx = base + grow;
                    int tok   = row_token[idx];
                    float wgt = row_wgt[idx];
                    int col = ct*128 + wc*64 + nn*16 + l15;
                    atomicAdd(out + (size_t)tok * K_DIM + col, wgt * acc[m][nn][r]);
                }
            }
#undef G2_LOAD
#undef G2_STORE
}

// ---------------------------------------------------------------------------
extern "C" void kernel_launch(void* const* d_in, const int* in_sizes, int n_in,
                              void* d_out, int out_size, void* d_ws, size_t ws_size,
                              hipStream_t stream)
{
    const float* X   = (const float*)d_in[0];
    const float* w1  = (const float*)d_in[1];
    const float* w2  = (const float*)d_in[2];
    const float* tw  = (const float*)d_in[3];
    const int*   ids = (const int*)d_in[4];   // int64 in reference -> int32 from harness
    float* out = (float*)d_out;

    // ws layout: act (bf16 4096x2816) | row_token | row_wgt | counts | offs
    bf16* act      = (bf16*)d_ws;
    int*  row_token= (int*)((char*)d_ws + (size_t)NROWS * DFF * sizeof(bf16));
    float* row_wgt = (float*)(row_token + NROWS);
    int*  counts   = (int*)(row_wgt + NROWS);
    int*  offs     = counts + E_NUM;

    hipMemsetAsync(d_out, 0, (size_t)out_size * sizeof(float), stream);
    route_kernel<<<1, 512, 0, stream>>>(ids, tw, counts, offs, row_token, row_wgt);
    gemm1_kernel<<<dim3(DFF/64, NROWS/128, E_NUM), 256, 0, stream>>>(X, w1, counts, offs, row_token, act);
    gemm2_kernel<<<dim3((K_DIM/128)*KSPLIT, NROWS/128, E_NUM), 256, 0, stream>>>(act, w2, counts, offs, row_token, row_wgt, out);
}